// Round 6
// baseline (315.679 us; speedup 1.0000x reference)
//
#include <hip/hip_runtime.h>
#include <math.h>
#include <stdint.h>

// Problem constants (fixed by setup_inputs)
#define E_EDGES 16384
#define H_DIM   256
#define S_SEEDS 32
#define NHEADS  8
#define HDIM    32
#define BGRAPHS 16
#define EPG     1024
#define N2      512       // v (256) | exp-scores (256)
#define NBLK    256       // == CU count: all blocks co-resident by construction
#define RSQRT_HD 0.17677669529663687f
#define BKP     40        // padded LDS k-stride (bf16 elems)
#define SMEM_BYTES 20480  // P1 As+Bs = 2*128*40*2B (max of phase union)

typedef __attribute__((ext_vector_type(8))) short bf16x8;
typedef __attribute__((ext_vector_type(4))) float f32x4;

__device__ inline unsigned short f2bf(float x) {            // round-to-nearest-even
    unsigned u = __float_as_uint(x);
    u += 0x7fff + ((u >> 16) & 1);
    return (unsigned short)(u >> 16);
}
__device__ inline float bf2f(unsigned int h) {
    return __uint_as_float((h & 0xffffu) << 16);
}

// Device-scope grid barrier. Single-use counter per phase (pre-zeroed by
// hipMemsetAsync). ACQ_REL arrive / ACQUIRE spin at AGENT scope gives
// cross-XCD release/acquire semantics (G16).
__device__ inline void gbar(int* bar, int idx) {
    __syncthreads();
    if (threadIdx.x == 0) {
        int* c = bar + idx * 16;                 // 64B apart
        __hip_atomic_fetch_add(c, 1, __ATOMIC_ACQ_REL, __HIP_MEMORY_SCOPE_AGENT);
        while (__hip_atomic_load(c, __ATOMIC_ACQUIRE, __HIP_MEMORY_SCOPE_AGENT) < NBLK)
            __builtin_amdgcn_s_sleep(8);
    }
    __syncthreads();
}

__device__ inline float block_sum256(float v, volatile float* red4) {
    for (int o = 32; o > 0; o >>= 1) v += __shfl_xor(v, o, 64);
    int wid = threadIdx.x >> 6;
    if ((threadIdx.x & 63) == 0) red4[wid] = v;
    __syncthreads();
    float r = red4[0] + red4[1] + red4[2] + red4[3];
    __syncthreads();
    return r;
}

// One persistent kernel, 256 blocks x 256 threads, manual grid barriers.
//  P0: WcT build (2 rows/block) + A->bf16 conv (den/att_raw/bar zeroed by memset)
//  P1: GEMM C[E,512] = Abf @ WcT^T (MFMA), 2 tiles/block; score tiles store
//      exp(score) and accumulate den[b][col] via wave-reduced atomics
//  P2: weighted-V partials (pre-exp'd p), 2 chunks/block, atomicAdd -> att_raw
//  P3: att_raw/den -> @Wo + residual + LayerNorm -> Y   (blocks 0..127)
//  P4: MLP1 partials, W1 read once                      (blocks 0..127)
//  P5: reduce + SiLU + @W2 + b2 -> out                  (blocks 0..15)
__global__ __launch_bounds__(256, 2) void mega(
        const float* __restrict__ ef,   const float* __restrict__ seed,
        const float* __restrict__ Wq,   const float* __restrict__ Wk,
        const float* __restrict__ Wv,   const float* __restrict__ Wo,
        const float* __restrict__ bo,   const float* __restrict__ ln_g,
        const float* __restrict__ ln_b, const float* __restrict__ W1,
        const float* __restrict__ b1,   const float* __restrict__ W2,
        const float* __restrict__ b2,   float* __restrict__ out,
        float* __restrict__ ws) {
    __shared__ __align__(16) char smem[SMEM_BYTES];
    float* smemf = (float*)smem;

    // workspace carve-up (bar+den+att_raw are the memset-zeroed prefix)
    int*   bar     = (int*)ws;                                   // 256 ints
    float* den     = ws + 256;                                   // [16][256]
    float* att_raw = den + BGRAPHS * H_DIM;                      // [512][256]
    float* Y       = att_raw + 512 * H_DIM;                      // [512][256]
    float* part    = Y + 512 * H_DIM;                            // [16][128][256]
    unsigned short* WcT = (unsigned short*)(part + 16 * 128 * H_DIM); // [512][256]
    unsigned short* Abf = WcT + 512 * H_DIM;                     // [16384][256]
    unsigned short* C   = Abf + (size_t)E_EDGES * H_DIM;         // [16384][512]

    int B = blockIdx.x, t = threadIdx.x;
    int gid = B * 256 + t;

    // ---------------- P0: prep ----------------
    {
        // A fp32 -> bf16: 524288 uint4-units (8 floats each), 8 per thread
        const float4* src = (const float4*)ef;
        uint4* dst = (uint4*)Abf;
        #pragma unroll
        for (int u = 0; u < 8; ++u) {
            size_t idx = (size_t)u * (NBLK * 256) + gid;
            float4 a = src[idx * 2], bq = src[idx * 2 + 1];
            uint4 o;
            o.x = (unsigned)f2bf(a.x)  | ((unsigned)f2bf(a.y)  << 16);
            o.y = (unsigned)f2bf(a.z)  | ((unsigned)f2bf(a.w)  << 16);
            o.z = (unsigned)f2bf(bq.x) | ((unsigned)f2bf(bq.y) << 16);
            o.w = (unsigned)f2bf(bq.z) | ((unsigned)f2bf(bq.w) << 16);
            dst[idx] = o;
        }
        // WcT row B (Wv columns; B < 256 always)
        WcT[B * H_DIM + t] = f2bf(Wv[t * H_DIM + B]);
        // WcT row B+256 (folded q@Wk score column; block-uniform path)
        {
            int c = B;                    // score col
            int h = c >> 5, s = c & 31;
            float* qrow = smemf;          // 32 floats
            if (t < HDIM) {
                float a = 0.f;
                for (int i = 0; i < H_DIM; ++i)
                    a = fmaf(seed[s * H_DIM + i], Wq[i * H_DIM + h * HDIM + t], a);
                qrow[t] = a * RSQRT_HD;   // fold 1/sqrt(hd)
            }
            __syncthreads();
            float a = 0.f;
            #pragma unroll
            for (int d = 0; d < HDIM; d += 4) {
                float4 w = *(const float4*)&Wk[t * H_DIM + h * HDIM + d];
                float4 qq = *(const float4*)&qrow[d];
                a = fmaf(w.x, qq.x, a); a = fmaf(w.y, qq.y, a);
                a = fmaf(w.z, qq.z, a); a = fmaf(w.w, qq.w, a);
            }
            WcT[(256 + B) * H_DIM + t] = f2bf(a);
        }
    }
    gbar(bar, 0);

    // ---------------- P1: MFMA GEMM + exp/den epilogue (2 tiles/block) ----------------
    {
        unsigned short* As = (unsigned short*)smem;        // 128*BKP u16
        unsigned short* Bs = As + 128 * BKP;
        int w = t >> 6, lane = t & 63;
        int wm = (w >> 1) * 64, wn = (w & 1) * 64;
        int lr = lane & 15, kg = lane >> 4;
        int srow = t >> 1, scol = (t & 1) * 16;
        for (int vt = 0; vt < 2; ++vt) {
            int tile = B + vt * NBLK;                      // 0..511
            int eb = tile >> 2, bn = tile & 3;
            int e0 = eb * 128, n0 = bn * 128;
            f32x4 acc[4][4] = {};
            for (int k0 = 0; k0 < H_DIM; k0 += 32) {
                const unsigned short* ap = &Abf[(size_t)(e0 + srow) * H_DIM + k0 + scol];
                const unsigned short* bp = &WcT[(size_t)(n0 + srow) * H_DIM + k0 + scol];
                uint4 av0 = *(const uint4*)(ap);
                uint4 av1 = *(const uint4*)(ap + 8);
                uint4 bv0 = *(const uint4*)(bp);
                uint4 bv1 = *(const uint4*)(bp + 8);
                __syncthreads();                           // prior frag reads done
                *(uint4*)&As[srow * BKP + scol]     = av0;
                *(uint4*)&As[srow * BKP + scol + 8] = av1;
                *(uint4*)&Bs[srow * BKP + scol]     = bv0;
                *(uint4*)&Bs[srow * BKP + scol + 8] = bv1;
                __syncthreads();
                bf16x8 af[4], bfv[4];
                #pragma unroll
                for (int mi = 0; mi < 4; ++mi)
                    af[mi] = *(const bf16x8*)&As[(wm + mi * 16 + lr) * BKP + kg * 8];
                #pragma unroll
                for (int ni = 0; ni < 4; ++ni)
                    bfv[ni] = *(const bf16x8*)&Bs[(wn + ni * 16 + lr) * BKP + kg * 8];
                #pragma unroll
                for (int mi = 0; mi < 4; ++mi)
                    #pragma unroll
                    for (int ni = 0; ni < 4; ++ni)
                        acc[mi][ni] = __builtin_amdgcn_mfma_f32_16x16x32_bf16(af[mi], bfv[ni], acc[mi][ni], 0, 0, 0);
            }
            // C/D layout: col = lane&15, row = (lane>>4)*4 + reg  [m89-verified]
            if (bn < 2) {                   // v columns: plain store
                #pragma unroll
                for (int mi = 0; mi < 4; ++mi)
                    #pragma unroll
                    for (int ni = 0; ni < 4; ++ni)
                        #pragma unroll
                        for (int r = 0; r < 4; ++r) {
                            int e = e0 + wm + mi * 16 + kg * 4 + r;
                            int n = n0 + wn + ni * 16 + lr;
                            C[(size_t)e * N2 + n] = f2bf(acc[mi][ni][r]);
                        }
            } else {                        // score columns: store exp, accumulate den
                int b = tile >> 5;          // graph of this 128-edge tile
                #pragma unroll
                for (int mi = 0; mi < 4; ++mi)
                    #pragma unroll
                    for (int ni = 0; ni < 4; ++ni)
                        #pragma unroll
                        for (int r = 0; r < 4; ++r) {
                            float ex = __expf(acc[mi][ni][r]);
                            acc[mi][ni][r] = ex;
                            int e = e0 + wm + mi * 16 + kg * 4 + r;
                            int n = n0 + wn + ni * 16 + lr;
                            C[(size_t)e * N2 + n] = f2bf(ex);
                        }
                #pragma unroll
                for (int ni = 0; ni < 4; ++ni) {
                    float cs = 0.f;
                    #pragma unroll
                    for (int mi = 0; mi < 4; ++mi)
                        #pragma unroll
                        for (int r = 0; r < 4; ++r) cs += acc[mi][ni][r];
                    cs += __shfl_xor(cs, 16, 64);
                    cs += __shfl_xor(cs, 32, 64);
                    if (kg == 0)
                        atomicAdd(&den[b * H_DIM + (n0 - H_DIM) + wn + ni * 16 + lr], cs);
                }
            }
        }
    }
    gbar(bar, 1);

    // ---------------- P2: weighted-V partials -> att_raw (2 vchunks/block) ----------------
    {
        int s = t & 31, dg = t >> 5;
        float* pbuf = smemf;                // [128][33] = 16896 B
        for (int vt = 0; vt < 2; ++vt) {
            int vb = B + vt * NBLK;         // 0..511
            int b = vb >> 5, rem = vb & 31;
            int h = rem >> 2, eq = rem & 3;
            int e0 = b * EPG + eq * 256;
            float a0 = 0.f, a1 = 0.f, a2 = 0.f, a3 = 0.f;
            #pragma unroll
            for (int cc = 0; cc < 2; ++cc) {
                int ec = e0 + cc * 128;
                __syncthreads();            // protect prior chunk's pbuf reads
                #pragma unroll
                for (int ii = 0; ii < 16; ++ii) {
                    int el = dg + 8 * ii;
                    pbuf[el * 33 + s] = bf2f(C[(size_t)(ec + el) * N2 + H_DIM + h * 32 + s]);
                }
                __syncthreads();
                for (int el = 0; el < 128; ++el) {
                    uint2 vv = *(const uint2*)&C[(size_t)(ec + el) * N2 + h * 32 + dg * 4];
                    float p = pbuf[el * 33 + s];
                    a0 = fmaf(p, bf2f(vv.x), a0);
                    a1 = fmaf(p, bf2f(vv.x >> 16), a1);
                    a2 = fmaf(p, bf2f(vv.y), a2);
                    a3 = fmaf(p, bf2f(vv.y >> 16), a3);
                }
            }
            float* ap = &att_raw[(size_t)(b * S_SEEDS + s) * H_DIM + h * 32 + dg * 4];
            atomicAdd(ap + 0, a0); atomicAdd(ap + 1, a1);
            atomicAdd(ap + 2, a2); atomicAdd(ap + 3, a3);
        }
    }
    gbar(bar, 2);

    // ---------------- P3: normalize + @Wo + residual + LN -> Y ----------------
    if (B < 128) {
        int bs0 = B * 4;
        int b = bs0 >> 5;
        int c = t;
        float* arow = smemf;                // [4][256]
        float* red4 = smemf + 4 * H_DIM;    // [4]
        #pragma unroll
        for (int r = 0; r < 4; ++r) {
            int bs = bs0 + r, s = bs & 31;
            float dn = den[b * H_DIM + ((c >> 5) << 5) + s];
            arow[r * H_DIM + c] = att_raw[(size_t)bs * H_DIM + c] / dn;
        }
        __syncthreads();
        float acc[4];
        float b0 = bo[c];
        #pragma unroll
        for (int r = 0; r < 4; ++r) acc[r] = b0;
        for (int i = 0; i < H_DIM; i += 4) {
            float4 a0 = *(const float4*)&arow[0 * H_DIM + i];
            float4 a1 = *(const float4*)&arow[1 * H_DIM + i];
            float4 a2 = *(const float4*)&arow[2 * H_DIM + i];
            float4 a3 = *(const float4*)&arow[3 * H_DIM + i];
            float w0 = Wo[(i + 0) * H_DIM + c], w1 = Wo[(i + 1) * H_DIM + c];
            float w2 = Wo[(i + 2) * H_DIM + c], w3 = Wo[(i + 3) * H_DIM + c];
            acc[0] = fmaf(a0.x, w0, acc[0]); acc[0] = fmaf(a0.y, w1, acc[0]);
            acc[0] = fmaf(a0.z, w2, acc[0]); acc[0] = fmaf(a0.w, w3, acc[0]);
            acc[1] = fmaf(a1.x, w0, acc[1]); acc[1] = fmaf(a1.y, w1, acc[1]);
            acc[1] = fmaf(a1.z, w2, acc[1]); acc[1] = fmaf(a1.w, w3, acc[1]);
            acc[2] = fmaf(a2.x, w0, acc[2]); acc[2] = fmaf(a2.y, w1, acc[2]);
            acc[2] = fmaf(a2.z, w2, acc[2]); acc[2] = fmaf(a2.w, w3, acc[2]);
            acc[3] = fmaf(a3.x, w0, acc[3]); acc[3] = fmaf(a3.y, w1, acc[3]);
            acc[3] = fmaf(a3.z, w2, acc[3]); acc[3] = fmaf(a3.w, w3, acc[3]);
        }
        float g = ln_g[c], be = ln_b[c];
        #pragma unroll
        for (int r = 0; r < 4; ++r) {
            int bs = bs0 + r;
            float y = seed[(bs & 31) * H_DIM + c] + acc[r];
            float mu = block_sum256(y, red4) * (1.f / 256.f);
            float d = y - mu;
            float var = block_sum256(d * d, red4) * (1.f / 256.f);
            Y[(size_t)bs * H_DIM + c] = d * rsqrtf(var + 1e-5f) * g + be;
        }
    }
    gbar(bar, 3);

    // ---------------- P4: MLP1 partials (W1 read once) ----------------
    if (B < 128) {
        int ch = B, c = t;
        int i0 = ch * 64;
        float* fbuf = smemf;                // [16][64]
        #pragma unroll
        for (int it = 0; it < 4; ++it) {
            int li = it * 256 + c;
            fbuf[(li >> 6) * 64 + (li & 63)] = Y[(size_t)(li >> 6) * 8192 + i0 + (li & 63)];
        }
        __syncthreads();
        float acc[16];
        #pragma unroll
        for (int b = 0; b < 16; ++b) acc[b] = 0.f;
        for (int ii = 0; ii < 64; ++ii) {
            float w = W1[(size_t)(i0 + ii) * H_DIM + c];
            #pragma unroll
            for (int b = 0; b < 16; ++b) acc[b] = fmaf(fbuf[b * 64 + ii], w, acc[b]);
        }
        #pragma unroll
        for (int b = 0; b < 16; ++b)
            part[((size_t)b * 128 + ch) * H_DIM + c] = acc[b];
    }
    gbar(bar, 4);

    // ---------------- P5: reduce + SiLU + @W2 + b2 -> out ----------------
    if (B < BGRAPHS) {
        int b = B, c = t;
        float s = b1[c];
        const float* pb = &part[(size_t)b * 128 * H_DIM + c];
        #pragma unroll 4
        for (int ch = 0; ch < 128; ++ch) s += pb[(size_t)ch * H_DIM];
        float h1 = s / (1.f + __expf(-s));
        float* hrow = smemf;
        hrow[c] = h1;
        __syncthreads();
        float acc = b2[c];
        for (int j = 0; j < H_DIM; j += 4) {
            float4 hq = *(const float4*)&hrow[j];
            acc = fmaf(hq.x, W2[(j + 0) * H_DIM + c], acc);
            acc = fmaf(hq.y, W2[(j + 1) * H_DIM + c], acc);
            acc = fmaf(hq.z, W2[(j + 2) * H_DIM + c], acc);
            acc = fmaf(hq.w, W2[(j + 3) * H_DIM + c], acc);
        }
        out[(size_t)b * H_DIM + c] = acc;
    }
}

extern "C" void kernel_launch(void* const* d_in, const int* in_sizes, int n_in,
                              void* d_out, int out_size, void* d_ws, size_t ws_size,
                              hipStream_t stream) {
    const float* ef   = (const float*)d_in[0];
    const float* seed = (const float*)d_in[3];
    const float* Wq   = (const float*)d_in[4];
    const float* Wk   = (const float*)d_in[5];
    const float* Wv   = (const float*)d_in[6];
    const float* Wo   = (const float*)d_in[7];
    const float* bo   = (const float*)d_in[8];
    const float* ln_g = (const float*)d_in[9];
    const float* ln_b = (const float*)d_in[10];
    const float* W1   = (const float*)d_in[11];
    const float* b1   = (const float*)d_in[12];
    const float* W2   = (const float*)d_in[13];
    const float* b2   = (const float*)d_in[14];
    float* out = (float*)d_out;
    float* ws  = (float*)d_ws;

    // Zero barrier counters + den + att_raw (ws is 0xAA-poisoned before every
    // timed call). (256 + 16*256 + 512*256) * 4 = 541,696 bytes.
    hipMemsetAsync(ws, 0, (256 + BGRAPHS * H_DIM + 512 * H_DIM) * sizeof(float), stream);
    mega<<<NBLK, 256, 0, stream>>>(ef, seed, Wq, Wk, Wv, Wo, bo, ln_g, ln_b,
                                   W1, b1, W2, b2, out, ws);
}

// Round 7
// 289.254 us; speedup vs baseline: 1.0914x; 1.0914x over previous
//
#include <hip/hip_runtime.h>
#include <math.h>
#include <stdint.h>

// Problem constants (fixed by setup_inputs)
#define E_EDGES 16384
#define H_DIM   256
#define S_SEEDS 32
#define NHEADS  8
#define HDIM    32
#define BGRAPHS 16
#define EPG     1024
#define N2      512       // v (256) | exp-scores (256)
#define NBLK    256       // == CU count: all blocks co-resident by construction
#define RSQRT_HD 0.17677669529663687f
#define BKP     40        // padded LDS k-stride (bf16 elems)
#define SMEM_BYTES 20480  // P1 As+Bs = 2*128*40*2B (max of phase union)

typedef __attribute__((ext_vector_type(8))) short bf16x8;
typedef __attribute__((ext_vector_type(4))) float f32x4;

__device__ inline unsigned short f2bf(float x) {            // round-to-nearest-even
    unsigned u = __float_as_uint(x);
    u += 0x7fff + ((u >> 16) & 1);
    return (unsigned short)(u >> 16);
}
__device__ inline float bf2f(unsigned int h) {
    return __uint_as_float((h & 0xffffu) << 16);
}

// Device-scope grid barrier, CHEAP form. Round-6 lesson: ACQUIRE load in the
// spin loop = L2-invalidate per poll across 8 XCDs -> ~40us/barrier storm.
// Correct form: ONE release fence before a RELAXED arrival add, RELAXED polls,
// ONE acquire fence after exit. Counters pre-zeroed by hipMemsetAsync.
__device__ inline void gbar(int* bar, int idx) {
    __syncthreads();
    if (threadIdx.x == 0) {
        int* c = bar + idx * 16;                 // 64B apart
        __threadfence();                         // release this phase's stores (agent)
        __hip_atomic_fetch_add(c, 1, __ATOMIC_RELAXED, __HIP_MEMORY_SCOPE_AGENT);
        while (__hip_atomic_load(c, __ATOMIC_RELAXED, __HIP_MEMORY_SCOPE_AGENT) < NBLK)
            __builtin_amdgcn_s_sleep(8);
        __threadfence();                         // acquire before next phase's reads
    }
    __syncthreads();
}

__device__ inline float block_sum256(float v, volatile float* red4) {
    for (int o = 32; o > 0; o >>= 1) v += __shfl_xor(v, o, 64);
    int wid = threadIdx.x >> 6;
    if ((threadIdx.x & 63) == 0) red4[wid] = v;
    __syncthreads();
    float r = red4[0] + red4[1] + red4[2] + red4[3];
    __syncthreads();
    return r;
}

// One persistent kernel, 256 blocks x 256 threads, manual grid barriers.
__global__ __launch_bounds__(256, 2) void mega(
        const float* __restrict__ ef,   const float* __restrict__ seed,
        const float* __restrict__ Wq,   const float* __restrict__ Wk,
        const float* __restrict__ Wv,   const float* __restrict__ Wo,
        const float* __restrict__ bo,   const float* __restrict__ ln_g,
        const float* __restrict__ ln_b, const float* __restrict__ W1,
        const float* __restrict__ b1,   const float* __restrict__ W2,
        const float* __restrict__ b2,   float* __restrict__ out,
        float* __restrict__ ws) {
    __shared__ __align__(16) char smem[SMEM_BYTES];
    float* smemf = (float*)smem;

    // workspace carve-up (bar+den+att_raw are the memset-zeroed prefix)
    int*   bar     = (int*)ws;                                   // 256 ints
    float* den     = ws + 256;                                   // [16][256]
    float* att_raw = den + BGRAPHS * H_DIM;                      // [512][256]
    float* Y       = att_raw + 512 * H_DIM;                      // [512][256]
    float* part    = Y + 512 * H_DIM;                            // [16][128][256]
    unsigned short* WcT = (unsigned short*)(part + 16 * 128 * H_DIM); // [512][256]
    unsigned short* Abf = WcT + 512 * H_DIM;                     // [16384][256]
    unsigned short* C   = Abf + (size_t)E_EDGES * H_DIM;         // [16384][512]

    int B = blockIdx.x, t = threadIdx.x;
    int gid = B * 256 + t;

    // ---------------- P0: prep ----------------
    {
        // A fp32 -> bf16: 524288 uint4-units (8 floats each), 8 per thread
        const float4* src = (const float4*)ef;
        uint4* dst = (uint4*)Abf;
        #pragma unroll
        for (int u = 0; u < 8; ++u) {
            size_t idx = (size_t)u * (NBLK * 256) + gid;
            float4 a = src[idx * 2], bq = src[idx * 2 + 1];
            uint4 o;
            o.x = (unsigned)f2bf(a.x)  | ((unsigned)f2bf(a.y)  << 16);
            o.y = (unsigned)f2bf(a.z)  | ((unsigned)f2bf(a.w)  << 16);
            o.z = (unsigned)f2bf(bq.x) | ((unsigned)f2bf(bq.y) << 16);
            o.w = (unsigned)f2bf(bq.z) | ((unsigned)f2bf(bq.w) << 16);
            dst[idx] = o;
        }
        // WcT row B (Wv columns; B < 256 always)
        WcT[B * H_DIM + t] = f2bf(Wv[t * H_DIM + B]);
        // WcT row B+256: folded q@Wk score column for (h,s) = (B>>5, B&31).
        // q[d] = sum_i seed[s,i]*Wq[i,h*32+d], computed with 8-way parallel
        // partials (round-6 version was a 256-iter serial loop on 32 threads
        // -> per-phase straggler that every barrier waited on).
        {
            int h = B >> 5, s = B & 31;
            int d = t & 31, g = t >> 5;            // 8 groups of 32
            float pa = 0.f;
            #pragma unroll
            for (int ii = 0; ii < 32; ++ii) {
                int i = g * 32 + ii;
                pa = fmaf(seed[s * H_DIM + i], Wq[i * H_DIM + h * HDIM + d], pa);
            }
            smemf[g * 32 + d] = pa;
            __syncthreads();
            if (t < HDIM) {
                float a = 0.f;
                #pragma unroll
                for (int g2 = 0; g2 < 8; ++g2) a += smemf[g2 * 32 + t];
                smemf[256 + t] = a * RSQRT_HD;     // qrow
            }
            __syncthreads();
            const float* qrow = smemf + 256;
            float a = 0.f;
            #pragma unroll
            for (int dd = 0; dd < HDIM; dd += 4) {
                float4 w = *(const float4*)&Wk[t * H_DIM + h * HDIM + dd];
                float4 qq = *(const float4*)&qrow[dd];
                a = fmaf(w.x, qq.x, a); a = fmaf(w.y, qq.y, a);
                a = fmaf(w.z, qq.z, a); a = fmaf(w.w, qq.w, a);
            }
            WcT[(256 + B) * H_DIM + t] = f2bf(a);
        }
    }
    gbar(bar, 0);

    // ---------------- P1: MFMA GEMM + exp/den epilogue (2 tiles/block) ----------------
    {
        unsigned short* As = (unsigned short*)smem;        // 128*BKP u16
        unsigned short* Bs = As + 128 * BKP;
        int w = t >> 6, lane = t & 63;
        int wm = (w >> 1) * 64, wn = (w & 1) * 64;
        int lr = lane & 15, kg = lane >> 4;
        int srow = t >> 1, scol = (t & 1) * 16;
        for (int vt = 0; vt < 2; ++vt) {
            int tile = B + vt * NBLK;                      // 0..511
            int eb = tile >> 2, bn = tile & 3;
            int e0 = eb * 128, n0 = bn * 128;
            const unsigned short* ap = &Abf[(size_t)(e0 + srow) * H_DIM + scol];
            const unsigned short* bp = &WcT[(size_t)(n0 + srow) * H_DIM + scol];
            // prefetch k0=0
            uint4 av0 = *(const uint4*)(ap);
            uint4 av1 = *(const uint4*)(ap + 8);
            uint4 bv0 = *(const uint4*)(bp);
            uint4 bv1 = *(const uint4*)(bp + 8);
            f32x4 acc[4][4] = {};
            for (int k0 = 0; k0 < H_DIM; k0 += 32) {
                __syncthreads();                           // prior frag reads done
                *(uint4*)&As[srow * BKP + scol]     = av0;
                *(uint4*)&As[srow * BKP + scol + 8] = av1;
                *(uint4*)&Bs[srow * BKP + scol]     = bv0;
                *(uint4*)&Bs[srow * BKP + scol + 8] = bv1;
                __syncthreads();
                if (k0 + 32 < H_DIM) {                     // software-pipeline next load
                    av0 = *(const uint4*)(ap + k0 + 32);
                    av1 = *(const uint4*)(ap + k0 + 40);
                    bv0 = *(const uint4*)(bp + k0 + 32);
                    bv1 = *(const uint4*)(bp + k0 + 40);
                }
                bf16x8 af[4], bfv[4];
                #pragma unroll
                for (int mi = 0; mi < 4; ++mi)
                    af[mi] = *(const bf16x8*)&As[(wm + mi * 16 + lr) * BKP + kg * 8];
                #pragma unroll
                for (int ni = 0; ni < 4; ++ni)
                    bfv[ni] = *(const bf16x8*)&Bs[(wn + ni * 16 + lr) * BKP + kg * 8];
                #pragma unroll
                for (int mi = 0; mi < 4; ++mi)
                    #pragma unroll
                    for (int ni = 0; ni < 4; ++ni)
                        acc[mi][ni] = __builtin_amdgcn_mfma_f32_16x16x32_bf16(af[mi], bfv[ni], acc[mi][ni], 0, 0, 0);
            }
            // C/D layout: col = lane&15, row = (lane>>4)*4 + reg  [m89-verified]
            if (bn < 2) {                   // v columns: plain store
                #pragma unroll
                for (int mi = 0; mi < 4; ++mi)
                    #pragma unroll
                    for (int ni = 0; ni < 4; ++ni)
                        #pragma unroll
                        for (int r = 0; r < 4; ++r) {
                            int e = e0 + wm + mi * 16 + kg * 4 + r;
                            int n = n0 + wn + ni * 16 + lr;
                            C[(size_t)e * N2 + n] = f2bf(acc[mi][ni][r]);
                        }
            } else {                        // score columns: store exp, accumulate den
                int b = tile >> 5;          // graph of this 128-edge tile
                #pragma unroll
                for (int mi = 0; mi < 4; ++mi)
                    #pragma unroll
                    for (int ni = 0; ni < 4; ++ni)
                        #pragma unroll
                        for (int r = 0; r < 4; ++r) {
                            float ex = __expf(acc[mi][ni][r]);
                            acc[mi][ni][r] = ex;
                            int e = e0 + wm + mi * 16 + kg * 4 + r;
                            int n = n0 + wn + ni * 16 + lr;
                            C[(size_t)e * N2 + n] = f2bf(ex);
                        }
                #pragma unroll
                for (int ni = 0; ni < 4; ++ni) {
                    float cs = 0.f;
                    #pragma unroll
                    for (int mi = 0; mi < 4; ++mi)
                        #pragma unroll
                        for (int r = 0; r < 4; ++r) cs += acc[mi][ni][r];
                    cs += __shfl_xor(cs, 16, 64);
                    cs += __shfl_xor(cs, 32, 64);
                    if (kg == 0)
                        atomicAdd(&den[b * H_DIM + (n0 - H_DIM) + wn + ni * 16 + lr], cs);
                }
            }
        }
    }
    gbar(bar, 1);

    // ---------------- P2: weighted-V partials -> att_raw (2 vchunks/block) ----------------
    {
        int s = t & 31, dg = t >> 5;
        float* pbuf = smemf;                // [128][33] = 16896 B
        for (int vt = 0; vt < 2; ++vt) {
            int vb = B + vt * NBLK;         // 0..511
            int b = vb >> 5, rem = vb & 31;
            int h = rem >> 2, eq = rem & 3;
            int e0 = b * EPG + eq * 256;
            float a0 = 0.f, a1 = 0.f, a2 = 0.f, a3 = 0.f;
            #pragma unroll
            for (int cc = 0; cc < 2; ++cc) {
                int ec = e0 + cc * 128;
                __syncthreads();            // protect prior chunk's pbuf reads
                #pragma unroll
                for (int ii = 0; ii < 16; ++ii) {
                    int el = dg + 8 * ii;
                    pbuf[el * 33 + s] = bf2f(C[(size_t)(ec + el) * N2 + H_DIM + h * 32 + s]);
                }
                __syncthreads();
                for (int el = 0; el < 128; ++el) {
                    uint2 vv = *(const uint2*)&C[(size_t)(ec + el) * N2 + h * 32 + dg * 4];
                    float p = pbuf[el * 33 + s];
                    a0 = fmaf(p, bf2f(vv.x), a0);
                    a1 = fmaf(p, bf2f(vv.x >> 16), a1);
                    a2 = fmaf(p, bf2f(vv.y), a2);
                    a3 = fmaf(p, bf2f(vv.y >> 16), a3);
                }
            }
            float* ap = &att_raw[(size_t)(b * S_SEEDS + s) * H_DIM + h * 32 + dg * 4];
            atomicAdd(ap + 0, a0); atomicAdd(ap + 1, a1);
            atomicAdd(ap + 2, a2); atomicAdd(ap + 3, a3);
        }
    }
    gbar(bar, 2);

    // ---------------- P3: normalize + @Wo + residual + LN -> Y ----------------
    if (B < 128) {
        int bs0 = B * 4;
        int b = bs0 >> 5;
        int c = t;
        float* arow = smemf;                // [4][256]
        float* red4 = smemf + 4 * H_DIM;    // [4]
        #pragma unroll
        for (int r = 0; r < 4; ++r) {
            int bs = bs0 + r, s = bs & 31;
            float dn = den[b * H_DIM + ((c >> 5) << 5) + s];
            arow[r * H_DIM + c] = att_raw[(size_t)bs * H_DIM + c] / dn;
        }
        __syncthreads();
        float acc[4];
        float b0 = bo[c];
        #pragma unroll
        for (int r = 0; r < 4; ++r) acc[r] = b0;
        for (int i = 0; i < H_DIM; i += 4) {
            float4 a0 = *(const float4*)&arow[0 * H_DIM + i];
            float4 a1 = *(const float4*)&arow[1 * H_DIM + i];
            float4 a2 = *(const float4*)&arow[2 * H_DIM + i];
            float4 a3 = *(const float4*)&arow[3 * H_DIM + i];
            float w0 = Wo[(i + 0) * H_DIM + c], w1 = Wo[(i + 1) * H_DIM + c];
            float w2 = Wo[(i + 2) * H_DIM + c], w3 = Wo[(i + 3) * H_DIM + c];
            acc[0] = fmaf(a0.x, w0, acc[0]); acc[0] = fmaf(a0.y, w1, acc[0]);
            acc[0] = fmaf(a0.z, w2, acc[0]); acc[0] = fmaf(a0.w, w3, acc[0]);
            acc[1] = fmaf(a1.x, w0, acc[1]); acc[1] = fmaf(a1.y, w1, acc[1]);
            acc[1] = fmaf(a1.z, w2, acc[1]); acc[1] = fmaf(a1.w, w3, acc[1]);
            acc[2] = fmaf(a2.x, w0, acc[2]); acc[2] = fmaf(a2.y, w1, acc[2]);
            acc[2] = fmaf(a2.z, w2, acc[2]); acc[2] = fmaf(a2.w, w3, acc[2]);
            acc[3] = fmaf(a3.x, w0, acc[3]); acc[3] = fmaf(a3.y, w1, acc[3]);
            acc[3] = fmaf(a3.z, w2, acc[3]); acc[3] = fmaf(a3.w, w3, acc[3]);
        }
        float g = ln_g[c], be = ln_b[c];
        #pragma unroll
        for (int r = 0; r < 4; ++r) {
            int bs = bs0 + r;
            float y = seed[(bs & 31) * H_DIM + c] + acc[r];
            float mu = block_sum256(y, red4) * (1.f / 256.f);
            float d = y - mu;
            float var = block_sum256(d * d, red4) * (1.f / 256.f);
            Y[(size_t)bs * H_DIM + c] = d * rsqrtf(var + 1e-5f) * g + be;
        }
    }
    gbar(bar, 3);

    // ---------------- P4: MLP1 partials (W1 read once) ----------------
    if (B < 128) {
        int ch = B, c = t;
        int i0 = ch * 64;
        float* fbuf = smemf;                // [16][64]
        #pragma unroll
        for (int it = 0; it < 4; ++it) {
            int li = it * 256 + c;
            fbuf[(li >> 6) * 64 + (li & 63)] = Y[(size_t)(li >> 6) * 8192 + i0 + (li & 63)];
        }
        __syncthreads();
        float acc[16];
        #pragma unroll
        for (int b = 0; b < 16; ++b) acc[b] = 0.f;
        for (int ii = 0; ii < 64; ++ii) {
            float w = W1[(size_t)(i0 + ii) * H_DIM + c];
            #pragma unroll
            for (int b = 0; b < 16; ++b) acc[b] = fmaf(fbuf[b * 64 + ii], w, acc[b]);
        }
        #pragma unroll
        for (int b = 0; b < 16; ++b)
            part[((size_t)b * 128 + ch) * H_DIM + c] = acc[b];
    }
    gbar(bar, 4);

    // ---------------- P5: reduce + SiLU + @W2 + b2 -> out ----------------
    if (B < BGRAPHS) {
        int b = B, c = t;
        float s = b1[c];
        const float* pb = &part[(size_t)b * 128 * H_DIM + c];
        #pragma unroll 4
        for (int ch = 0; ch < 128; ++ch) s += pb[(size_t)ch * H_DIM];
        float h1 = s / (1.f + __expf(-s));
        float* hrow = smemf;
        hrow[c] = h1;
        __syncthreads();
        float acc = b2[c];
        for (int j = 0; j < H_DIM; j += 4) {
            float4 hq = *(const float4*)&hrow[j];
            acc = fmaf(hq.x, W2[(j + 0) * H_DIM + c], acc);
            acc = fmaf(hq.y, W2[(j + 1) * H_DIM + c], acc);
            acc = fmaf(hq.z, W2[(j + 2) * H_DIM + c], acc);
            acc = fmaf(hq.w, W2[(j + 3) * H_DIM + c], acc);
        }
        out[(size_t)b * H_DIM + c] = acc;
    }
}

extern "C" void kernel_launch(void* const* d_in, const int* in_sizes, int n_in,
                              void* d_out, int out_size, void* d_ws, size_t ws_size,
                              hipStream_t stream) {
    const float* ef   = (const float*)d_in[0];
    const float* seed = (const float*)d_in[3];
    const float* Wq   = (const float*)d_in[4];
    const float* Wk   = (const float*)d_in[5];
    const float* Wv   = (const float*)d_in[6];
    const float* Wo   = (const float*)d_in[7];
    const float* bo   = (const float*)d_in[8];
    const float* ln_g = (const float*)d_in[9];
    const float* ln_b = (const float*)d_in[10];
    const float* W1   = (const float*)d_in[11];
    const float* b1   = (const float*)d_in[12];
    const float* W2   = (const float*)d_in[13];
    const float* b2   = (const float*)d_in[14];
    float* out = (float*)d_out;
    float* ws  = (float*)d_ws;

    // Zero barrier counters + den + att_raw (ws is 0xAA-poisoned before every
    // timed call). (256 + 16*256 + 512*256) * 4 = 541,696 bytes.
    hipMemsetAsync(ws, 0, (256 + BGRAPHS * H_DIM + 512 * H_DIM) * sizeof(float), stream);
    mega<<<NBLK, 256, 0, stream>>>(ef, seed, Wq, Wk, Wv, Wo, bo, ln_g, ln_b,
                                   W1, b1, W2, b2, out, ws);
}